// Round 7
// baseline (328.498 us; speedup 1.0000x reference)
//
#include <hip/hip_runtime.h>
#include <hip/hip_fp16.h>

#define N_NODES 100000
#define N_EDGES 1600000
#define NBUCK 196            // ceil(N_NODES / 512); bucket = dst >> 9
#define BUCAP 10240          // per-bucket capacity (mean 8192, sigma ~90: +22 sigma)
#define P1_EDGES 8192        // edges per P1 block
#define NP1 196              // ceil(N_EDGES / P1_EDGES)
#define CURPAD 32            // cursor stride (ints): one 128B line per bucket

// ---------------------------------------------------------------------------
// CSR build, atomic-light bucket sort (rebuilt every launch; ws re-poisoned).
// ---------------------------------------------------------------------------
__global__ __launch_bounds__(256) void k_zero_cur(int* __restrict__ cursor) {
    if (threadIdx.x < NBUCK) cursor[threadIdx.x * CURPAD] = 0;
}

__global__ __launch_bounds__(1024) void k_p1(const int* __restrict__ ei,
                                             int* __restrict__ cursor,
                                             int* __restrict__ bArr) {
    __shared__ int hist[NBUCK];
    const int tid = threadIdx.x;
    if (tid < NBUCK) hist[tid] = 0;

    const int eb = blockIdx.x * P1_EDGES;
    int d[8], s[8];
    #pragma unroll
    for (int j = 0; j < 2; ++j) {
        const int e = eb + j * 4096 + tid * 4;
        if (e < N_EDGES) {                       // N_EDGES % 4 == 0: all-or-none
            int4 dd = *(const int4*)&ei[N_EDGES + e];
            int4 ss = *(const int4*)&ei[e];
            d[j*4+0] = dd.x; d[j*4+1] = dd.y; d[j*4+2] = dd.z; d[j*4+3] = dd.w;
            s[j*4+0] = ss.x; s[j*4+1] = ss.y; s[j*4+2] = ss.z; s[j*4+3] = ss.w;
        } else {
            d[j*4+0] = -1; d[j*4+1] = -1; d[j*4+2] = -1; d[j*4+3] = -1;
            s[j*4+0] = 0;  s[j*4+1] = 0;  s[j*4+2] = 0;  s[j*4+3] = 0;
        }
    }
    __syncthreads();
    #pragma unroll
    for (int j = 0; j < 8; ++j)
        if (d[j] >= 0) atomicAdd(&hist[d[j] >> 9], 1);
    __syncthreads();
    if (tid < NBUCK) {
        int c = hist[tid];
        int base = atomicAdd(&cursor[tid * CURPAD], c);  // padded: no line sharing
        hist[tid] = base;                                // reuse hist as write cursor
    }
    __syncthreads();
    #pragma unroll
    for (int j = 0; j < 8; ++j)
        if (d[j] >= 0) {
            int bk  = d[j] >> 9;
            int pos = atomicAdd(&hist[bk], 1);   // LDS rank -> base+rank
            if (pos < BUCAP)
                bArr[bk * BUCAP + pos] = ((d[j] & 511) << 17) | s[j];
        }
}

__global__ __launch_bounds__(1024) void k_p2(const int* __restrict__ bArr,
                                             const int* __restrict__ cursor,
                                             int* __restrict__ srcS,
                                             int* __restrict__ off) {
    __shared__ int hist[512];
    __shared__ int wtot[8];
    __shared__ int curL[NBUCK];
    __shared__ int ordered[BUCAP];
    const int tid = threadIdx.x;
    const int b   = blockIdx.x;
    if (tid < 512)   hist[tid] = 0;
    if (tid < NBUCK) curL[tid] = cursor[tid * CURPAD];
    __syncthreads();

    int n = curL[b]; if (n > BUCAP) n = BUCAP;
    int gBase = 0;
    for (int j = 0; j < NBUCK; ++j) gBase += (j < b) ? curL[j] : 0;   // LDS broadcast

    int pk[10];                                  // static-indexed (rule #20)
    #pragma unroll
    for (int j = 0; j < 10; ++j) {
        int i = tid + j * 1024;
        pk[j] = (i < n) ? bArr[b * BUCAP + i] : -1;
    }
    #pragma unroll
    for (int j = 0; j < 10; ++j)
        if (pk[j] >= 0) atomicAdd(&hist[pk[j] >> 17], 1);
    __syncthreads();

    // exclusive scan of hist[512]: 8 waves shfl-scan + cross-wave fixup
    int v = 0, incl = 0;
    if (tid < 512) {
        v = hist[tid]; incl = v;
        #pragma unroll
        for (int dd = 1; dd < 64; dd <<= 1) {
            int t = __shfl_up(incl, dd, 64);
            if ((tid & 63) >= dd) incl += t;
        }
        if ((tid & 63) == 63) wtot[tid >> 6] = incl;
    }
    __syncthreads();
    if (tid < 512) {
        int add = 0;
        #pragma unroll
        for (int w = 0; w < 8; ++w) add += (w < (tid >> 6)) ? wtot[w] : 0;
        int ex = add + incl - v;
        hist[tid] = ex;                          // becomes rank cursor for phase B
        int node = b * 512 + tid;
        if (node < N_NODES) off[node] = gBase + ex;
    }
    if (b == NBUCK - 1 && tid == 0) off[N_NODES] = N_EDGES;
    __syncthreads();

    #pragma unroll
    for (int j = 0; j < 10; ++j)
        if (pk[j] >= 0) {
            int dl  = pk[j] >> 17;
            int pos = atomicAdd(&hist[dl], 1);
            ordered[pos] = pk[j] & 0x1FFFF;
        }
    __syncthreads();
    for (int i = tid; i < n; i += 1024) srcS[gBase + i] = ordered[i];
}

// ---------------------------------------------------------------------------
// Gather core v2 (fp16 rows, 8 lanes/row x 16B): one wave per node, split
// into 8 groups of 8 lanes; group g fetches edge (burst_base + g), lane slot
// s8 = lane&7 holds 16B = 8 channels. One uint4 load instruction covers 8
// rows -> a 4-deep burst keeps 32 edges (32x128B requests) in flight/wave.
// Result: after the xor(8,16,32) butterfly, EVERY lane holds the summed
// channels s8*8 .. s8*8+7 (replicated across groups). fp32 accumulate.
// ---------------------------------------------------------------------------
union UH { unsigned u; __half2 h; };
struct Acc8 { float2 a0, a1, a2, a3; };

__device__ __forceinline__ void add8(Acc8& A, uint4 q) {
    UH u0, u1, u2, u3;
    u0.u = q.x; u1.u = q.y; u2.u = q.z; u3.u = q.w;
    float2 f0 = __half22float2(u0.h), f1 = __half22float2(u1.h);
    float2 f2 = __half22float2(u2.h), f3 = __half22float2(u3.h);
    A.a0.x += f0.x; A.a0.y += f0.y; A.a1.x += f1.x; A.a1.y += f1.y;
    A.a2.x += f2.x; A.a2.y += f2.y; A.a3.x += f3.x; A.a3.y += f3.y;
}

__device__ __forceinline__ Acc8 gather_core8(const int* __restrict__ off,
                                             const int* __restrict__ srcS,
                                             const __half* __restrict__ y16,
                                             int node, int lane) {
    const int g   = lane >> 3;
    const int s8  = lane & 7;
    const int bo  = s8 << 3;                     // channel offset of this 16B slice
    const int beg = off[node];
    const int end = off[node + 1];

    Acc8 A = {{0.f,0.f},{0.f,0.f},{0.f,0.f},{0.f,0.f}};
    if (g == 0)                                  // self term: one group only
        add8(A, *(const uint4*)&y16[((size_t)node << 6) + bo]);

    int i = beg;
    while (i < end) {
        const int rem  = end - i;
        const int take = rem < 64 ? rem : 64;
        int idx = i + lane;
        if (idx > end - 1) idx = end - 1;        // in-range duplicate for lanes >= take
        const int sv = srcS[idx];                // coalesced: 64 edge indices / wave
        int j = 0;
        for (; j + 32 <= take; j += 32) {        // 32 edges = 32 requests in flight
            const int e0 = __shfl(sv, j + g);
            const int e1 = __shfl(sv, j + 8 + g);
            const int e2 = __shfl(sv, j + 16 + g);
            const int e3 = __shfl(sv, j + 24 + g);
            const uint4 q0 = *(const uint4*)&y16[((size_t)e0 << 6) + bo];
            const uint4 q1 = *(const uint4*)&y16[((size_t)e1 << 6) + bo];
            const uint4 q2 = *(const uint4*)&y16[((size_t)e2 << 6) + bo];
            const uint4 q3 = *(const uint4*)&y16[((size_t)e3 << 6) + bo];
            add8(A, q0); add8(A, q1); add8(A, q2); add8(A, q3);
        }
        for (; j + 16 <= take; j += 16) {
            const int e0 = __shfl(sv, j + g);
            const int e1 = __shfl(sv, j + 8 + g);
            const uint4 q0 = *(const uint4*)&y16[((size_t)e0 << 6) + bo];
            const uint4 q1 = *(const uint4*)&y16[((size_t)e1 << 6) + bo];
            add8(A, q0); add8(A, q1);
        }
        for (; j < take; j += 8) {               // predicated tail burst
            int jj = j + g;
            const bool vld = (jj < take);
            if (jj > take - 1) jj = take - 1;
            const int e = __shfl(sv, jj);
            const uint4 q = *(const uint4*)&y16[((size_t)e << 6) + bo];
            if (vld) add8(A, q);
        }
        i += take;
    }
    // combine the 8 groups: butterfly over lane bits 3..5
    #pragma unroll
    for (int d = 8; d < 64; d <<= 1) {
        A.a0.x += __shfl_xor(A.a0.x, d, 64); A.a0.y += __shfl_xor(A.a0.y, d, 64);
        A.a1.x += __shfl_xor(A.a1.x, d, 64); A.a1.y += __shfl_xor(A.a1.y, d, 64);
        A.a2.x += __shfl_xor(A.a2.x, d, 64); A.a2.y += __shfl_xor(A.a2.y, d, 64);
        A.a3.x += __shfl_xor(A.a3.x, d, 64); A.a3.y += __shfl_xor(A.a3.y, d, 64);
    }
    return A;
}

// ---------------------------------------------------------------------------
// Gather1 fused epilogue: h1 = relu(agg(y1) + b1) stored as fp16.
// Lanes 0-7 store 16B each = one coalesced 128B row.
// ---------------------------------------------------------------------------
__global__ __launch_bounds__(256) void k_gather_h1(const int* __restrict__ off,
                                                   const int* __restrict__ srcS,
                                                   const __half* __restrict__ y16,
                                                   const float* __restrict__ b1,
                                                   __half* __restrict__ h16) {
    const int node = blockIdx.x * 4 + (threadIdx.x >> 6);
    if (node >= N_NODES) return;
    const int lane = threadIdx.x & 63;
    const int g = lane >> 3, s8 = lane & 7;

    Acc8 A = gather_core8(off, srcS, y16, node, lane);

    if (g == 0) {
        const float4 bA = *(const float4*)&b1[s8 * 8];
        const float4 bB = *(const float4*)&b1[s8 * 8 + 4];
        UH o0, o1, o2, o3;
        o0.h = __floats2half2_rn(fmaxf(A.a0.x + bA.x, 0.f), fmaxf(A.a0.y + bA.y, 0.f));
        o1.h = __floats2half2_rn(fmaxf(A.a1.x + bA.z, 0.f), fmaxf(A.a1.y + bA.w, 0.f));
        o2.h = __floats2half2_rn(fmaxf(A.a2.x + bB.x, 0.f), fmaxf(A.a2.y + bB.y, 0.f));
        o3.h = __floats2half2_rn(fmaxf(A.a3.x + bB.z, 0.f), fmaxf(A.a3.y + bB.w, 0.f));
        uint4 q = {o0.u, o1.u, o2.u, o3.u};
        *(uint4*)&h16[((size_t)node << 6) + (s8 << 3)] = q;
    }
}

// ---------------------------------------------------------------------------
// Gather2 fused with the MLP head (z2 never materializes), now LDS-free:
// after the butterfly every lane holds its 8-channel slice replicated, so
// h2->h3 is 16 FMAs/lane + xor(1,2,4) reduce; W4-dot + xor(8,16,32).
// W3 slices preload BEFORE the gather (hides under memory waits).
// All-fp32 head math, same as the reference tail.
// ---------------------------------------------------------------------------
__global__ __launch_bounds__(256) void k_gather_tail(const int* __restrict__ off,
                                                     const int* __restrict__ srcS,
                                                     const __half* __restrict__ y16,
                                                     const float* __restrict__ b2,
                                                     const float* __restrict__ W3,
                                                     const float* __restrict__ b3,
                                                     const float* __restrict__ W4,
                                                     const float* __restrict__ b4,
                                                     float* __restrict__ out) {
    const int node = blockIdx.x * 4 + (threadIdx.x >> 6);
    if (node >= N_NODES) return;
    const int lane = threadIdx.x & 63;
    const int g = lane >> 3, s8 = lane & 7;

    // this lane's W3 slice: rows s8*8..+7, cols 2g and 2g+1 (L2-hot, 4KB)
    float w3a[8], w3b[8];
    #pragma unroll
    for (int k = 0; k < 8; ++k) {
        w3a[k] = W3[(s8 * 8 + k) * 16 + g * 2];
        w3b[k] = W3[(s8 * 8 + k) * 16 + g * 2 + 1];
    }

    Acc8 A = gather_core8(off, srcS, y16, node, lane);

    const float4 bA = *(const float4*)&b2[s8 * 8];
    const float4 bB = *(const float4*)&b2[s8 * 8 + 4];
    const float h0 = fmaxf(A.a0.x + bA.x, 0.f), h1 = fmaxf(A.a0.y + bA.y, 0.f);
    const float h2 = fmaxf(A.a1.x + bA.z, 0.f), h3 = fmaxf(A.a1.y + bA.w, 0.f);
    const float h4 = fmaxf(A.a2.x + bB.x, 0.f), h5 = fmaxf(A.a2.y + bB.y, 0.f);
    const float h6 = fmaxf(A.a3.x + bB.z, 0.f), h7 = fmaxf(A.a3.y + bB.w, 0.f);

    float p0 = h0*w3a[0] + h1*w3a[1] + h2*w3a[2] + h3*w3a[3]
             + h4*w3a[4] + h5*w3a[5] + h6*w3a[6] + h7*w3a[7];
    float p1 = h0*w3b[0] + h1*w3b[1] + h2*w3b[2] + h3*w3b[3]
             + h4*w3b[4] + h5*w3b[5] + h6*w3b[6] + h7*w3b[7];
    #pragma unroll
    for (int d = 1; d < 8; d <<= 1) {            // reduce over channel slices
        p0 += __shfl_xor(p0, d, 64);
        p1 += __shfl_xor(p1, d, 64);
    }
    float o = fmaxf(p0 + b3[g * 2], 0.f)     * W4[g * 2]
            + fmaxf(p1 + b3[g * 2 + 1], 0.f) * W4[g * 2 + 1];
    #pragma unroll
    for (int d = 8; d < 64; d <<= 1) o += __shfl_xor(o, d, 64);  // over j-pairs
    if (lane == 0) out[node] = o + b4[0];
}

// ---------------------------------------------------------------------------
// K1: y16 = fp16(x @ W1)  (N x 128 @ 128 x 64).  64x64 block tile, 4x4
// register tile, X staged transposed in LDS.
// ---------------------------------------------------------------------------
#define FMA16()                                                       \
    do {                                                              \
        acc0.x += a.x * w.x; acc0.y += a.x * w.y;                     \
        acc0.z += a.x * w.z; acc0.w += a.x * w.w;                     \
        acc1.x += a.y * w.x; acc1.y += a.y * w.y;                     \
        acc1.z += a.y * w.z; acc1.w += a.y * w.w;                     \
        acc2.x += a.z * w.x; acc2.y += a.z * w.y;                     \
        acc2.z += a.z * w.z; acc2.w += a.z * w.w;                     \
        acc3.x += a.w * w.x; acc3.y += a.w * w.y;                     \
        acc3.z += a.w * w.z; acc3.w += a.w * w.w;                     \
    } while (0)

__device__ __forceinline__ void store_h4(__half* p, float4 a) {
    union { __half2 h[2]; uint2 u; } P;
    P.h[0] = __floats2half2_rn(a.x, a.y);
    P.h[1] = __floats2half2_rn(a.z, a.w);
    *(uint2*)p = P.u;
}

__global__ __launch_bounds__(256) void k_mm1(const float* __restrict__ x,
                                             const float* __restrict__ W1,
                                             __half* __restrict__ y16) {
    __shared__ float sW[128 * 64];    // 32 KB, [k][n]
    __shared__ float sxT[128 * 68];   // 34 KB, [k][m] transposed, stride 68
    const int tid  = threadIdx.x;
    const int row0 = blockIdx.x * 64;
    #pragma unroll
    for (int i = tid * 4; i < 128 * 64; i += 1024)
        *(float4*)&sW[i] = *(const float4*)&W1[i];
    #pragma unroll 8
    for (int i = tid; i < 64 * 128; i += 256) {
        int m = i >> 7, k = i & 127;                 // coalesced in k
        int r = row0 + m; if (r >= N_NODES) r = N_NODES - 1;
        sxT[k * 68 + m] = x[(size_t)r * 128 + k];
    }
    __syncthreads();
    const int tx = tid & 15;          // cols tx*4 .. +3
    const int ty = tid >> 4;          // rows ty*4 .. +3
    float4 acc0 = {0.f,0.f,0.f,0.f}, acc1 = {0.f,0.f,0.f,0.f};
    float4 acc2 = {0.f,0.f,0.f,0.f}, acc3 = {0.f,0.f,0.f,0.f};
    #pragma unroll 4
    for (int k = 0; k < 128; ++k) {
        float4 a = *(const float4*)&sxT[k * 68 + ty * 4];
        float4 w = *(const float4*)&sW[k * 64 + tx * 4];
        FMA16();
    }
    const int rb = row0 + ty * 4;
    if (rb + 0 < N_NODES) store_h4(&y16[(size_t)(rb + 0) * 64 + tx * 4], acc0);
    if (rb + 1 < N_NODES) store_h4(&y16[(size_t)(rb + 1) * 64 + tx * 4], acc1);
    if (rb + 2 < N_NODES) store_h4(&y16[(size_t)(rb + 2) * 64 + tx * 4], acc2);
    if (rb + 3 < N_NODES) store_h4(&y16[(size_t)(rb + 3) * 64 + tx * 4], acc3);
}

// ---------------------------------------------------------------------------
// K3: y16 = fp16(h1 @ W2)  (64x64).  h1 comes in fp16 (relu/bias already
// applied by k_gather_h1).
// ---------------------------------------------------------------------------
__global__ __launch_bounds__(256) void k_mm2(const __half* __restrict__ h16,
                                             const float* __restrict__ W2,
                                             __half* __restrict__ y16) {
    __shared__ float sW[64 * 64];     // 16 KB, [k][n]
    __shared__ float shT[64 * 68];    // 17 KB, [k][m] transposed
    const int tid  = threadIdx.x;
    const int row0 = blockIdx.x * 64;
    #pragma unroll
    for (int i = tid * 4; i < 64 * 64; i += 1024)
        *(float4*)&sW[i] = *(const float4*)&W2[i];
    #pragma unroll
    for (int i = tid * 2; i < 64 * 64; i += 512) {
        int m = i >> 6, k = i & 63;                  // coalesced in k (half2)
        int r = row0 + m; if (r >= N_NODES) r = N_NODES - 1;
        __half2 hv = *(const __half2*)&h16[(size_t)r * 64 + k];
        float2 f = __half22float2(hv);
        shT[k * 68 + m]       = f.x;
        shT[(k + 1) * 68 + m] = f.y;
    }
    __syncthreads();
    const int tx = tid & 15;
    const int ty = tid >> 4;
    float4 acc0 = {0.f,0.f,0.f,0.f}, acc1 = {0.f,0.f,0.f,0.f};
    float4 acc2 = {0.f,0.f,0.f,0.f}, acc3 = {0.f,0.f,0.f,0.f};
    #pragma unroll 4
    for (int k = 0; k < 64; ++k) {
        float4 a = *(const float4*)&shT[k * 68 + ty * 4];
        float4 w = *(const float4*)&sW[k * 64 + tx * 4];
        FMA16();
    }
    const int rb = row0 + ty * 4;
    if (rb + 0 < N_NODES) store_h4(&y16[(size_t)(rb + 0) * 64 + tx * 4], acc0);
    if (rb + 1 < N_NODES) store_h4(&y16[(size_t)(rb + 1) * 64 + tx * 4], acc1);
    if (rb + 2 < N_NODES) store_h4(&y16[(size_t)(rb + 2) * 64 + tx * 4], acc2);
    if (rb + 3 < N_NODES) store_h4(&y16[(size_t)(rb + 3) * 64 + tx * 4], acc3);
}

extern "C" void kernel_launch(void* const* d_in, const int* in_sizes, int n_in,
                              void* d_out, int out_size, void* d_ws, size_t ws_size,
                              hipStream_t stream) {
    const float* x  = (const float*)d_in[0];
    const int*   ei = (const int*)d_in[1];
    const float* W1 = (const float*)d_in[2];
    const float* b1 = (const float*)d_in[3];
    const float* W2 = (const float*)d_in[4];
    const float* b2 = (const float*)d_in[5];
    const float* W3 = (const float*)d_in[6];
    const float* b3 = (const float*)d_in[7];
    const float* W4 = (const float*)d_in[8];
    const float* b4 = (const float*)d_in[9];
    float* out = (float*)d_out;

    // ws layout: h16 (12.8MB, aliases bArr 8MB) | y16 (12.8MB) | off | srcS | cursor
    // Order: p1/p2 use bArr -> mm1 writes y16 -> gather_h1 reads y16, writes
    // h16 (p2 done) -> mm2 reads h16, writes y16 (y1 dead) -> gather_tail.
    __half* h16    = (__half*)d_ws;
    __half* y16    = h16 + (size_t)N_NODES * 64;
    int*    off    = (int*)(y16 + (size_t)N_NODES * 64);
    int*    srcS   = off + N_NODES + 4;       // 16B alignment slack
    int*    cursor = srcS + N_EDGES;
    int*    bArr   = (int*)d_ws;

    const int mmBlocks  = (N_NODES + 63) / 64;        // 1563
    const int aggBlocks = (N_NODES + 3) / 4;          // 25000

    // CSR build (bucket sort, LDS atomics only)
    k_zero_cur<<<1, 256, 0, stream>>>(cursor);
    k_p1<<<NP1, 1024, 0, stream>>>(ei, cursor, bArr);
    k_p2<<<NBUCK, 1024, 0, stream>>>(bArr, cursor, srcS, off);

    // conv1: y16 = fp16(x@W1); h16 = fp16(relu(agg(y16)+b1))
    k_mm1<<<mmBlocks, 256, 0, stream>>>(x, W1, y16);
    k_gather_h1<<<aggBlocks, 256, 0, stream>>>(off, srcS, y16, b1, h16);
    // conv2 + head: y16 = fp16(h16@W2); out = head(agg(y16))
    k_mm2<<<mmBlocks, 256, 0, stream>>>(h16, W2, y16);
    k_gather_tail<<<aggBlocks, 256, 0, stream>>>(off, srcS, y16, b2, W3, b3, W4, b4, out);
}

// Round 9
// 254.906 us; speedup vs baseline: 1.2887x; 1.2887x over previous
//
#include <hip/hip_runtime.h>
#include <hip/hip_fp16.h>

#define N_NODES 100000
#define N_EDGES 1600000
#define NBUCK 196            // ceil(N_NODES / 512); bucket = dst >> 9
#define BUCAP 10240          // per-bucket capacity (mean 8192, sigma ~90: +22 sigma)
#define P1_EDGES 8192        // edges per P1 block
#define NP1 196              // ceil(N_EDGES / P1_EDGES)
#define CURPAD 32            // cursor stride (ints): one 128B line per bucket

typedef _Float16 f16x8 __attribute__((ext_vector_type(8)));
typedef float    f32x4 __attribute__((ext_vector_type(4)));

// ---------------------------------------------------------------------------
// CSR build, atomic-light bucket sort (rebuilt every launch; ws re-poisoned).
// ---------------------------------------------------------------------------
__global__ __launch_bounds__(256) void k_zero_cur(int* __restrict__ cursor) {
    if (threadIdx.x < NBUCK) cursor[threadIdx.x * CURPAD] = 0;
}

__global__ __launch_bounds__(1024) void k_p1(const int* __restrict__ ei,
                                             int* __restrict__ cursor,
                                             int* __restrict__ bArr) {
    __shared__ int hist[NBUCK];
    const int tid = threadIdx.x;
    if (tid < NBUCK) hist[tid] = 0;

    const int eb = blockIdx.x * P1_EDGES;
    int d[8], s[8];
    #pragma unroll
    for (int j = 0; j < 2; ++j) {
        const int e = eb + j * 4096 + tid * 4;
        if (e < N_EDGES) {                       // N_EDGES % 4 == 0: all-or-none
            int4 dd = *(const int4*)&ei[N_EDGES + e];
            int4 ss = *(const int4*)&ei[e];
            d[j*4+0] = dd.x; d[j*4+1] = dd.y; d[j*4+2] = dd.z; d[j*4+3] = dd.w;
            s[j*4+0] = ss.x; s[j*4+1] = ss.y; s[j*4+2] = ss.z; s[j*4+3] = ss.w;
        } else {
            d[j*4+0] = -1; d[j*4+1] = -1; d[j*4+2] = -1; d[j*4+3] = -1;
            s[j*4+0] = 0;  s[j*4+1] = 0;  s[j*4+2] = 0;  s[j*4+3] = 0;
        }
    }
    __syncthreads();
    #pragma unroll
    for (int j = 0; j < 8; ++j)
        if (d[j] >= 0) atomicAdd(&hist[d[j] >> 9], 1);
    __syncthreads();
    if (tid < NBUCK) {
        int c = hist[tid];
        int base = atomicAdd(&cursor[tid * CURPAD], c);  // padded: no line sharing
        hist[tid] = base;                                // reuse hist as write cursor
    }
    __syncthreads();
    #pragma unroll
    for (int j = 0; j < 8; ++j)
        if (d[j] >= 0) {
            int bk  = d[j] >> 9;
            int pos = atomicAdd(&hist[bk], 1);   // LDS rank -> base+rank
            if (pos < BUCAP)
                bArr[bk * BUCAP + pos] = ((d[j] & 511) << 17) | s[j];
        }
}

__global__ __launch_bounds__(1024) void k_p2(const int* __restrict__ bArr,
                                             const int* __restrict__ cursor,
                                             int* __restrict__ srcS,
                                             int* __restrict__ off) {
    __shared__ int hist[512];
    __shared__ int wtot[8];
    __shared__ int curL[NBUCK];
    __shared__ int ordered[BUCAP];
    const int tid = threadIdx.x;
    const int b   = blockIdx.x;
    if (tid < 512)   hist[tid] = 0;
    if (tid < NBUCK) curL[tid] = cursor[tid * CURPAD];
    __syncthreads();

    int n = curL[b]; if (n > BUCAP) n = BUCAP;
    int gBase = 0;
    for (int j = 0; j < NBUCK; ++j) gBase += (j < b) ? curL[j] : 0;   // LDS broadcast

    int pk[10];                                  // static-indexed (rule #20)
    #pragma unroll
    for (int j = 0; j < 10; ++j) {
        int i = tid + j * 1024;
        pk[j] = (i < n) ? bArr[b * BUCAP + i] : -1;
    }
    #pragma unroll
    for (int j = 0; j < 10; ++j)
        if (pk[j] >= 0) atomicAdd(&hist[pk[j] >> 17], 1);
    __syncthreads();

    // exclusive scan of hist[512]: 8 waves shfl-scan + cross-wave fixup
    int v = 0, incl = 0;
    if (tid < 512) {
        v = hist[tid]; incl = v;
        #pragma unroll
        for (int dd = 1; dd < 64; dd <<= 1) {
            int t = __shfl_up(incl, dd, 64);
            if ((tid & 63) >= dd) incl += t;
        }
        if ((tid & 63) == 63) wtot[tid >> 6] = incl;
    }
    __syncthreads();
    if (tid < 512) {
        int add = 0;
        #pragma unroll
        for (int w = 0; w < 8; ++w) add += (w < (tid >> 6)) ? wtot[w] : 0;
        int ex = add + incl - v;
        hist[tid] = ex;                          // becomes rank cursor for phase B
        int node = b * 512 + tid;
        if (node < N_NODES) off[node] = gBase + ex;
    }
    if (b == NBUCK - 1 && tid == 0) off[N_NODES] = N_EDGES;
    __syncthreads();

    #pragma unroll
    for (int j = 0; j < 10; ++j)
        if (pk[j] >= 0) {
            int dl  = pk[j] >> 17;
            int pos = atomicAdd(&hist[dl], 1);
            ordered[pos] = pk[j] & 0x1FFFF;
        }
    __syncthreads();
    for (int i = tid; i < n; i += 1024) srcS[gBase + i] = ordered[i];
}

// ---------------------------------------------------------------------------
// Gather core (round-5 proven structure): fp16 rows, 32 lanes/row x half2.
// Wave splits into two halves, each gathering its own edge of a pair: 8
// dword loads in flight per 16-edge burst (degree ~16 => one full burst).
// Returns per-lane float2 BEFORE the half-combine.
// ---------------------------------------------------------------------------
__device__ __forceinline__ float2 gather_core(const int* __restrict__ off,
                                              const int* __restrict__ srcS,
                                              const __half* __restrict__ y16,
                                              int node, int lane) {
    const int hf   = lane >> 5;
    const int ln32 = lane & 31;
    const int beg = off[node];
    const int end = off[node + 1];

    float2 acc = {0.f, 0.f};
    if (hf == 0) {                               // self term
        __half2 hv = *(const __half2*)&y16[((size_t)node << 6) + (ln32 << 1)];
        float2 f = __half22float2(hv);
        acc.x = f.x; acc.y = f.y;
    }

    int i = beg;
    while (i < end) {
        const int rem  = end - i;
        const int take = rem < 64 ? rem : 64;
        int idx = i + lane;
        if (idx > end - 1) idx = end - 1;        // in-range duplicate for lanes >= take
        const int sv = srcS[idx];                // coalesced: 64 edge indices / wave
        int j = 0;
        for (; j + 16 <= take; j += 16) {        // 8 pairs = 16 edges, 8 loads in flight
            const int s0 = __shfl(sv, j + 0  + hf), s1 = __shfl(sv, j + 2  + hf);
            const int s2 = __shfl(sv, j + 4  + hf), s3 = __shfl(sv, j + 6  + hf);
            const int s4 = __shfl(sv, j + 8  + hf), s5 = __shfl(sv, j + 10 + hf);
            const int s6 = __shfl(sv, j + 12 + hf), s7 = __shfl(sv, j + 14 + hf);
            const __half2 h0 = *(const __half2*)&y16[((size_t)s0 << 6) + (ln32 << 1)];
            const __half2 h1 = *(const __half2*)&y16[((size_t)s1 << 6) + (ln32 << 1)];
            const __half2 h2 = *(const __half2*)&y16[((size_t)s2 << 6) + (ln32 << 1)];
            const __half2 h3 = *(const __half2*)&y16[((size_t)s3 << 6) + (ln32 << 1)];
            const __half2 h4 = *(const __half2*)&y16[((size_t)s4 << 6) + (ln32 << 1)];
            const __half2 h5 = *(const __half2*)&y16[((size_t)s5 << 6) + (ln32 << 1)];
            const __half2 h6 = *(const __half2*)&y16[((size_t)s6 << 6) + (ln32 << 1)];
            const __half2 h7 = *(const __half2*)&y16[((size_t)s7 << 6) + (ln32 << 1)];
            float2 f0 = __half22float2(h0), f1 = __half22float2(h1);
            float2 f2 = __half22float2(h2), f3 = __half22float2(h3);
            float2 f4 = __half22float2(h4), f5 = __half22float2(h5);
            float2 f6 = __half22float2(h6), f7 = __half22float2(h7);
            acc.x += ((f0.x + f1.x) + (f2.x + f3.x)) + ((f4.x + f5.x) + (f6.x + f7.x));
            acc.y += ((f0.y + f1.y) + (f2.y + f3.y)) + ((f4.y + f5.y) + (f6.y + f7.y));
        }
        for (; j + 2 <= take; j += 2) {
            const int s = __shfl(sv, j + hf);
            const __half2 hv = *(const __half2*)&y16[((size_t)s << 6) + (ln32 << 1)];
            float2 f = __half22float2(hv);
            acc.x += f.x; acc.y += f.y;
        }
        if (j < take) {                          // odd leftover: hf==0 half handles it
            const int s = __shfl(sv, j);
            if (hf == 0) {
                const __half2 hv = *(const __half2*)&y16[((size_t)s << 6) + (ln32 << 1)];
                float2 f = __half22float2(hv);
                acc.x += f.x; acc.y += f.y;
            }
        }
        i += take;
    }
    return acc;
}

// ---------------------------------------------------------------------------
// Gather1 fused epilogue: h1 = relu(agg(y1) + b1) stored as fp16 (12.8 MB).
// ---------------------------------------------------------------------------
__global__ __launch_bounds__(256) void k_gather_h1(const int* __restrict__ off,
                                                   const int* __restrict__ srcS,
                                                   const __half* __restrict__ y16,
                                                   const float* __restrict__ b1,
                                                   __half* __restrict__ h16) {
    const int node = blockIdx.x * 4 + (threadIdx.x >> 6);
    if (node >= N_NODES) return;
    const int lane = threadIdx.x & 63;
    const int hf = lane >> 5, ln32 = lane & 31;
    float2 bb = {0.f, 0.f};
    if (hf == 0) bb = *(const float2*)&b1[ln32 * 2];

    float2 acc = gather_core(off, srcS, y16, node, lane);
    acc.x += __shfl_xor(acc.x, 32, 64);
    acc.y += __shfl_xor(acc.y, 32, 64);
    if (hf == 0) {
        float hx = fmaxf(acc.x + bb.x, 0.f);
        float hy = fmaxf(acc.y + bb.y, 0.f);
        *(__half2*)&h16[((size_t)node << 6) + (ln32 << 1)] = __floats2half2_rn(hx, hy);
    }
}

// ---------------------------------------------------------------------------
// Gather2 fused with the whole MLP head (z2 never materializes):
// z2 = agg(y2); h2 = relu(z2+b2); h3 = relu(h2@W3+b3); out = h3@W4+b4.
// Head in-wave: row exchanged via 1KB intra-wave LDS, 4 lanes per W3-column
// (W3 slices preloaded BEFORE the gather -> hidden), shfl_xor reductions.
// ---------------------------------------------------------------------------
__global__ __launch_bounds__(256) void k_gather_tail(const int* __restrict__ off,
                                                     const int* __restrict__ srcS,
                                                     const __half* __restrict__ y16,
                                                     const float* __restrict__ b2,
                                                     const float* __restrict__ W3,
                                                     const float* __restrict__ b3,
                                                     const float* __restrict__ W4,
                                                     const float* __restrict__ b4,
                                                     float* __restrict__ out) {
    __shared__ float sh2[4][64];
    const int wv   = threadIdx.x >> 6;
    const int node = blockIdx.x * 4 + wv;
    if (node >= N_NODES) return;
    const int lane = threadIdx.x & 63;
    const int hf = lane >> 5, ln32 = lane & 31;

    const int jj = lane & 15, pp = lane >> 4;    // 4 lanes cooperate per output jj
    float w3r[16];
    #pragma unroll
    for (int k = 0; k < 16; ++k) w3r[k] = W3[(pp * 16 + k) * 16 + jj];
    const float b3j = b3[jj], w4j = W4[jj], b4v = b4[0];
    float2 bb = {0.f, 0.f};
    if (hf == 0) bb = *(const float2*)&b2[ln32 * 2];

    float2 acc = gather_core(off, srcS, y16, node, lane);
    acc.x += __shfl_xor(acc.x, 32, 64);
    acc.y += __shfl_xor(acc.y, 32, 64);
    if (hf == 0) {
        float hx = fmaxf(acc.x + bb.x, 0.f);
        float hy = fmaxf(acc.y + bb.y, 0.f);
        *(float2*)&sh2[wv][ln32 * 2] = make_float2(hx, hy);
    }
    // intra-wave LDS exchange: per-wave DS ordering makes the write visible
    // to this wave's reads (no cross-wave consumers -> no barrier).
    const float4 hA = *(const float4*)&sh2[wv][pp * 16 + 0];
    const float4 hB = *(const float4*)&sh2[wv][pp * 16 + 4];
    const float4 hC = *(const float4*)&sh2[wv][pp * 16 + 8];
    const float4 hD = *(const float4*)&sh2[wv][pp * 16 + 12];
    float part = hA.x * w3r[0]  + hA.y * w3r[1]  + hA.z * w3r[2]  + hA.w * w3r[3]
               + hB.x * w3r[4]  + hB.y * w3r[5]  + hB.z * w3r[6]  + hB.w * w3r[7]
               + hC.x * w3r[8]  + hC.y * w3r[9]  + hC.z * w3r[10] + hC.w * w3r[11]
               + hD.x * w3r[12] + hD.y * w3r[13] + hD.z * w3r[14] + hD.w * w3r[15];
    part += __shfl_xor(part, 16, 64);            // reduce over pp (bits 4,5)
    part += __shfl_xor(part, 32, 64);
    float o = fmaxf(part + b3j, 0.f) * w4j;
    o += __shfl_xor(o, 1, 64);                   // reduce over jj (bits 0..3)
    o += __shfl_xor(o, 2, 64);
    o += __shfl_xor(o, 4, 64);
    o += __shfl_xor(o, 8, 64);
    if (lane == 0) out[node] = o + b4v;
}

// ---------------------------------------------------------------------------
// K1 (MFMA): y16 = fp16(x @ W1), 64 rows/block, 4 waves x 16 rows.
// A (node rows) has no cross-wave reuse -> loaded DIRECTLY from global
// (fp32, cvt in regs). Only W1^T is staged in LDS (fp16, [n][k] stride 136:
// 272B rows = 16B-aligned, 2-way bank conflict max).
// mfma_f32_16x16x32_f16: A row=l&15, k=(l>>4)*8+i; B col=l&15, same k;
// D col=l&15, row=(l>>4)*4+reg (m89-verified mapping).
// ---------------------------------------------------------------------------
__global__ __launch_bounds__(256) void k_mm1(const float* __restrict__ x,
                                             const float* __restrict__ W1,
                                             __half* __restrict__ y16) {
    __shared__ __half sB[64 * 136];   // W1^T: sB[n][k], 17.4 KB
    const int tid = threadIdx.x;
    for (int i = tid * 4; i < 128 * 64; i += 1024) {
        int k = i >> 6, n = i & 63;                  // i = k*64 + n
        float4 w = *(const float4*)&W1[i];
        sB[(n + 0) * 136 + k] = __float2half(w.x);
        sB[(n + 1) * 136 + k] = __float2half(w.y);
        sB[(n + 2) * 136 + k] = __float2half(w.z);
        sB[(n + 3) * 136 + k] = __float2half(w.w);
    }
    __syncthreads();
    const int wv = tid >> 6, l = tid & 63;
    const int row0 = blockIdx.x * 64 + wv * 16;
    int arow = row0 + (l & 15);
    if (arow >= N_NODES) arow = N_NODES - 1;         // duplicate last row (stores predicated)
    const int kgrp = (l >> 4) * 8;

    f32x4 acc0 = {0,0,0,0}, acc1 = {0,0,0,0}, acc2 = {0,0,0,0}, acc3 = {0,0,0,0};
    #pragma unroll
    for (int ks = 0; ks < 4; ++ks) {
        const float4 a0 = *(const float4*)&x[(size_t)arow * 128 + ks * 32 + kgrp];
        const float4 a1 = *(const float4*)&x[(size_t)arow * 128 + ks * 32 + kgrp + 4];
        f16x8 af;
        af[0] = (_Float16)a0.x; af[1] = (_Float16)a0.y;
        af[2] = (_Float16)a0.z; af[3] = (_Float16)a0.w;
        af[4] = (_Float16)a1.x; af[5] = (_Float16)a1.y;
        af[6] = (_Float16)a1.z; af[7] = (_Float16)a1.w;
        union { uint4 u; f16x8 h; } B0, B1, B2, B3;
        B0.u = *(const uint4*)&sB[(0 * 16 + (l & 15)) * 136 + ks * 32 + kgrp];
        B1.u = *(const uint4*)&sB[(1 * 16 + (l & 15)) * 136 + ks * 32 + kgrp];
        B2.u = *(const uint4*)&sB[(2 * 16 + (l & 15)) * 136 + ks * 32 + kgrp];
        B3.u = *(const uint4*)&sB[(3 * 16 + (l & 15)) * 136 + ks * 32 + kgrp];
        acc0 = __builtin_amdgcn_mfma_f32_16x16x32_f16(af, B0.h, acc0, 0, 0, 0);
        acc1 = __builtin_amdgcn_mfma_f32_16x16x32_f16(af, B1.h, acc1, 0, 0, 0);
        acc2 = __builtin_amdgcn_mfma_f32_16x16x32_f16(af, B2.h, acc2, 0, 0, 0);
        acc3 = __builtin_amdgcn_mfma_f32_16x16x32_f16(af, B3.h, acc3, 0, 0, 0);
    }
    #pragma unroll
    for (int rr = 0; rr < 4; ++rr) {
        const int orow = row0 + (l >> 4) * 4 + rr;
        if (orow < N_NODES) {
            __half* yp = &y16[(size_t)orow * 64 + (l & 15)];
            yp[0]  = __float2half(acc0[rr]);
            yp[16] = __float2half(acc1[rr]);
            yp[32] = __float2half(acc2[rr]);
            yp[48] = __float2half(acc3[rr]);
        }
    }
}

// ---------------------------------------------------------------------------
// K3 (MFMA): y16 = fp16(h16 @ W2), K=64. A direct from global (already fp16,
// one dwordx4 per k-step). W2^T staged fp16 in LDS (stride 72: 144B rows).
// ---------------------------------------------------------------------------
__global__ __launch_bounds__(256) void k_mm2(const __half* __restrict__ h16,
                                             const float* __restrict__ W2,
                                             __half* __restrict__ y16) {
    __shared__ __half sB[64 * 72];    // W2^T: sB[n][k], 9.2 KB
    const int tid = threadIdx.x;
    for (int i = tid * 4; i < 64 * 64; i += 1024) {
        int k = i >> 6, n = i & 63;                  // i = k*64 + n
        float4 w = *(const float4*)&W2[i];
        sB[(n + 0) * 72 + k] = __float2half(w.x);
        sB[(n + 1) * 72 + k] = __float2half(w.y);
        sB[(n + 2) * 72 + k] = __float2half(w.z);
        sB[(n + 3) * 72 + k] = __float2half(w.w);
    }
    __syncthreads();
    const int wv = tid >> 6, l = tid & 63;
    const int row0 = blockIdx.x * 64 + wv * 16;
    int arow = row0 + (l & 15);
    if (arow >= N_NODES) arow = N_NODES - 1;
    const int kgrp = (l >> 4) * 8;

    f32x4 acc0 = {0,0,0,0}, acc1 = {0,0,0,0}, acc2 = {0,0,0,0}, acc3 = {0,0,0,0};
    #pragma unroll
    for (int ks = 0; ks < 2; ++ks) {
        union { uint4 u; f16x8 h; } A;
        A.u = *(const uint4*)&h16[(size_t)arow * 64 + ks * 32 + kgrp];
        union { uint4 u; f16x8 h; } B0, B1, B2, B3;
        B0.u = *(const uint4*)&sB[(0 * 16 + (l & 15)) * 72 + ks * 32 + kgrp];
        B1.u = *(const uint4*)&sB[(1 * 16 + (l & 15)) * 72 + ks * 32 + kgrp];
        B2.u = *(const uint4*)&sB[(2 * 16 + (l & 15)) * 72 + ks * 32 + kgrp];
        B3.u = *(const uint4*)&sB[(3 * 16 + (l & 15)) * 72 + ks * 32 + kgrp];
        acc0 = __builtin_amdgcn_mfma_f32_16x16x32_f16(A.h, B0.h, acc0, 0, 0, 0);
        acc1 = __builtin_amdgcn_mfma_f32_16x16x32_f16(A.h, B1.h, acc1, 0, 0, 0);
        acc2 = __builtin_amdgcn_mfma_f32_16x16x32_f16(A.h, B2.h, acc2, 0, 0, 0);
        acc3 = __builtin_amdgcn_mfma_f32_16x16x32_f16(A.h, B3.h, acc3, 0, 0, 0);
    }
    #pragma unroll
    for (int rr = 0; rr < 4; ++rr) {
        const int orow = row0 + (l >> 4) * 4 + rr;
        if (orow < N_NODES) {
            __half* yp = &y16[(size_t)orow * 64 + (l & 15)];
            yp[0]  = __float2half(acc0[rr]);
            yp[16] = __float2half(acc1[rr]);
            yp[32] = __float2half(acc2[rr]);
            yp[48] = __float2half(acc3[rr]);
        }
    }
}

extern "C" void kernel_launch(void* const* d_in, const int* in_sizes, int n_in,
                              void* d_out, int out_size, void* d_ws, size_t ws_size,
                              hipStream_t stream) {
    const float* x  = (const float*)d_in[0];
    const int*   ei = (const int*)d_in[1];
    const float* W1 = (const float*)d_in[2];
    const float* b1 = (const float*)d_in[3];
    const float* W2 = (const float*)d_in[4];
    const float* b2 = (const float*)d_in[5];
    const float* W3 = (const float*)d_in[6];
    const float* b3 = (const float*)d_in[7];
    const float* W4 = (const float*)d_in[8];
    const float* b4 = (const float*)d_in[9];
    float* out = (float*)d_out;

    // ws layout: h16 (12.8MB, aliases bArr 8MB) | y16 (12.8MB) | off | srcS | cursor
    // Order: p1/p2 use bArr -> mm1 writes y16 -> gather_h1 reads y16, writes
    // h16 (p2 done) -> mm2 reads h16, writes y16 (y1 dead) -> gather_tail.
    __half* h16    = (__half*)d_ws;
    __half* y16    = h16 + (size_t)N_NODES * 64;
    int*    off    = (int*)(y16 + (size_t)N_NODES * 64);
    int*    srcS   = off + N_NODES + 4;       // 16B alignment slack
    int*    cursor = srcS + N_EDGES;
    int*    bArr   = (int*)d_ws;

    const int mmBlocks  = (N_NODES + 63) / 64;        // 1563
    const int aggBlocks = (N_NODES + 3) / 4;          // 25000

    // CSR build (bucket sort, LDS atomics only)
    k_zero_cur<<<1, 256, 0, stream>>>(cursor);
    k_p1<<<NP1, 1024, 0, stream>>>(ei, cursor, bArr);
    k_p2<<<NBUCK, 1024, 0, stream>>>(bArr, cursor, srcS, off);

    // conv1: y16 = fp16(x@W1); h16 = fp16(relu(agg(y16)+b1))
    k_mm1<<<mmBlocks, 256, 0, stream>>>(x, W1, y16);
    k_gather_h1<<<aggBlocks, 256, 0, stream>>>(off, srcS, y16, b1, h16);
    // conv2 + head: y16 = fp16(h16@W2); out = head(agg(y16))
    k_mm2<<<mmBlocks, 256, 0, stream>>>(h16, W2, y16);
    k_gather_tail<<<aggBlocks, 256, 0, stream>>>(off, srcS, y16, b2, W3, b3, W4, b4, out);
}

// Round 10
// 250.845 us; speedup vs baseline: 1.3096x; 1.0162x over previous
//
#include <hip/hip_runtime.h>
#include <hip/hip_fp16.h>

#define N_NODES 100000
#define N_EDGES 1600000
#define NBUCK 196            // ceil(N_NODES / 512); bucket = dst >> 9
#define BUCAP 10240          // per-bucket capacity (mean 8163, sigma ~90)
#define P1_EDGES 4096        // edges per P1 block (391 blocks -> all CUs busy)
#define NP1 391              // ceil(N_EDGES / P1_EDGES)
#define CURPAD 32            // cursor stride (ints): one 128B line per bucket

typedef _Float16 f16x8 __attribute__((ext_vector_type(8)));
typedef float    f32x4 __attribute__((ext_vector_type(4)));

// ---------------------------------------------------------------------------
// CSR build, atomic-light bucket sort (rebuilt every launch; ws re-poisoned).
// ---------------------------------------------------------------------------
__global__ __launch_bounds__(256) void k_zero_cur(int* __restrict__ cursor) {
    if (threadIdx.x < NBUCK) cursor[threadIdx.x * CURPAD] = 0;
}

// P1 v2: LDS-staged bucket scatter. Edges are ranked and packed bucket-ordered
// in LDS (p2's proven pattern), then copied out in ~21-edge contiguous runs so
// consecutive lanes write consecutive bArr addresses (was: 4B random scatter).
__global__ __launch_bounds__(1024) void k_p1(const int* __restrict__ ei,
                                             int* __restrict__ cursor,
                                             int* __restrict__ bArr) {
    __shared__ int hist[NBUCK];
    __shared__ int lcur[NBUCK];
    __shared__ int gdb[NBUCK];
    __shared__ int lim[NBUCK];
    __shared__ int stage[P1_EDGES];
    __shared__ int sdest[P1_EDGES];
    __shared__ int sTot;
    const int tid = threadIdx.x;
    if (tid < NBUCK) hist[tid] = 0;

    const int e = blockIdx.x * P1_EDGES + tid * 4;
    int4 dd = {-1, -1, -1, -1}, ss = {0, 0, 0, 0};
    if (e < N_EDGES) {                           // N_EDGES % 4 == 0: all-or-none
        dd = *(const int4*)&ei[N_EDGES + e];
        ss = *(const int4*)&ei[e];
    }
    __syncthreads();
    int d[4] = {dd.x, dd.y, dd.z, dd.w};
    int s[4] = {ss.x, ss.y, ss.z, ss.w};
    #pragma unroll
    for (int j = 0; j < 4; ++j)
        if (d[j] >= 0) atomicAdd(&hist[d[j] >> 9], 1);
    __syncthreads();
    if (tid < NBUCK) {
        int c  = hist[tid];
        int lb = 0;
        for (int j = 0; j < NBUCK; ++j) lb += (j < tid) ? hist[j] : 0;
        if (tid == NBUCK - 1) sTot = lb + c;
        int g = atomicAdd(&cursor[tid * CURPAD], c);   // one global atomic/bucket
        lcur[tid] = lb;                                // local rank cursor
        gdb[tid]  = tid * BUCAP + g - lb;              // dest = gdb[bk] + lpos
        lim[tid]  = tid * BUCAP + BUCAP;
    }
    __syncthreads();
    #pragma unroll
    for (int j = 0; j < 4; ++j)
        if (d[j] >= 0) {
            int bk   = d[j] >> 9;
            int lpos = atomicAdd(&lcur[bk], 1);
            int dest = gdb[bk] + lpos;
            stage[lpos] = ((d[j] & 511) << 17) | s[j];
            sdest[lpos] = (dest < lim[bk]) ? dest : -1;    // BUCAP insurance
        }
    __syncthreads();
    const int tot = sTot;
    for (int i = tid; i < tot; i += 1024) {
        int dst = sdest[i];
        if (dst >= 0) bArr[dst] = stage[i];      // run-coalesced (bucket-ordered)
    }
}

__global__ __launch_bounds__(1024) void k_p2(const int* __restrict__ bArr,
                                             const int* __restrict__ cursor,
                                             int* __restrict__ srcS,
                                             int* __restrict__ off) {
    __shared__ int hist[512];
    __shared__ int wtot[8];
    __shared__ int curL[NBUCK];
    __shared__ int ordered[BUCAP];
    const int tid = threadIdx.x;
    const int b   = blockIdx.x;
    if (tid < 512)   hist[tid] = 0;
    if (tid < NBUCK) curL[tid] = cursor[tid * CURPAD];
    __syncthreads();

    int n = curL[b]; if (n > BUCAP) n = BUCAP;
    int gBase = 0;
    for (int j = 0; j < NBUCK; ++j) gBase += (j < b) ? curL[j] : 0;   // LDS broadcast

    int pk[10];                                  // static-indexed (rule #20)
    #pragma unroll
    for (int j = 0; j < 10; ++j) {
        int i = tid + j * 1024;
        pk[j] = (i < n) ? bArr[b * BUCAP + i] : -1;
    }
    #pragma unroll
    for (int j = 0; j < 10; ++j)
        if (pk[j] >= 0) atomicAdd(&hist[pk[j] >> 17], 1);
    __syncthreads();

    // exclusive scan of hist[512]: 8 waves shfl-scan + cross-wave fixup
    int v = 0, incl = 0;
    if (tid < 512) {
        v = hist[tid]; incl = v;
        #pragma unroll
        for (int dd = 1; dd < 64; dd <<= 1) {
            int t = __shfl_up(incl, dd, 64);
            if ((tid & 63) >= dd) incl += t;
        }
        if ((tid & 63) == 63) wtot[tid >> 6] = incl;
    }
    __syncthreads();
    if (tid < 512) {
        int add = 0;
        #pragma unroll
        for (int w = 0; w < 8; ++w) add += (w < (tid >> 6)) ? wtot[w] : 0;
        int ex = add + incl - v;
        hist[tid] = ex;                          // becomes rank cursor for phase B
        int node = b * 512 + tid;
        if (node < N_NODES) off[node] = gBase + ex;
    }
    if (b == NBUCK - 1 && tid == 0) off[N_NODES] = N_EDGES;
    __syncthreads();

    #pragma unroll
    for (int j = 0; j < 10; ++j)
        if (pk[j] >= 0) {
            int dl  = pk[j] >> 17;
            int pos = atomicAdd(&hist[dl], 1);
            ordered[pos] = pk[j] & 0x1FFFF;
        }
    __syncthreads();
    for (int i = tid; i < n; i += 1024) srcS[gBase + i] = ordered[i];
}

// ---------------------------------------------------------------------------
// Gather core: fp16 rows, 32 lanes/row x half2; wave splits into two halves,
// each gathering its own edge of a pair (8 loads in flight / 16-edge burst).
// v3: (a) edge-pair pre-add in fp16 (__hadd2; sums bounded ~60 << 65504),
// (b) 32-bit byte-offset addressing (SGPR base + voffset, 1 VALU per addr).
// Returns per-lane float2 BEFORE the half-combine.
// ---------------------------------------------------------------------------
__device__ __forceinline__ float2 gather_core(const int* __restrict__ off,
                                              const int* __restrict__ srcS,
                                              const __half* __restrict__ y16,
                                              int node, int lane) {
    const int hf   = lane >> 5;
    const int ln32 = lane & 31;
    const unsigned co = (unsigned)(ln32 << 2);   // byte offset within 128B row
    const char* yb = (const char*)y16;
    const int beg = off[node];
    const int end = off[node + 1];

    float2 acc = {0.f, 0.f};
    if (hf == 0) {                               // self term
        __half2 hv = *(const __half2*)(yb + (((unsigned)node << 7) | co));
        float2 f = __half22float2(hv);
        acc.x = f.x; acc.y = f.y;
    }

    int i = beg;
    while (i < end) {
        const int rem  = end - i;
        const int take = rem < 64 ? rem : 64;
        int idx = i + lane;
        if (idx > end - 1) idx = end - 1;        // in-range duplicate for lanes >= take
        const int sv = srcS[idx];                // coalesced: 64 edge indices / wave
        int j = 0;
        for (; j + 16 <= take; j += 16) {        // 8 pairs = 16 edges, 8 loads in flight
            const int s0 = __shfl(sv, j + 0  + hf), s1 = __shfl(sv, j + 2  + hf);
            const int s2 = __shfl(sv, j + 4  + hf), s3 = __shfl(sv, j + 6  + hf);
            const int s4 = __shfl(sv, j + 8  + hf), s5 = __shfl(sv, j + 10 + hf);
            const int s6 = __shfl(sv, j + 12 + hf), s7 = __shfl(sv, j + 14 + hf);
            const __half2 h0 = *(const __half2*)(yb + (((unsigned)s0 << 7) | co));
            const __half2 h1 = *(const __half2*)(yb + (((unsigned)s1 << 7) | co));
            const __half2 h2 = *(const __half2*)(yb + (((unsigned)s2 << 7) | co));
            const __half2 h3 = *(const __half2*)(yb + (((unsigned)s3 << 7) | co));
            const __half2 h4 = *(const __half2*)(yb + (((unsigned)s4 << 7) | co));
            const __half2 h5 = *(const __half2*)(yb + (((unsigned)s5 << 7) | co));
            const __half2 h6 = *(const __half2*)(yb + (((unsigned)s6 << 7) | co));
            const __half2 h7 = *(const __half2*)(yb + (((unsigned)s7 << 7) | co));
            const __half2 t0 = __hadd2(h0, h1);  // fp16 pair pre-add (v_pk_add_f16)
            const __half2 t1 = __hadd2(h2, h3);
            const __half2 t2 = __hadd2(h4, h5);
            const __half2 t3 = __hadd2(h6, h7);
            float2 f0 = __half22float2(t0), f1 = __half22float2(t1);
            float2 f2 = __half22float2(t2), f3 = __half22float2(t3);
            acc.x += (f0.x + f1.x) + (f2.x + f3.x);
            acc.y += (f0.y + f1.y) + (f2.y + f3.y);
        }
        for (; j + 2 <= take; j += 2) {
            const int s = __shfl(sv, j + hf);
            const __half2 hv = *(const __half2*)(yb + (((unsigned)s << 7) | co));
            float2 f = __half22float2(hv);
            acc.x += f.x; acc.y += f.y;
        }
        if (j < take) {                          // odd leftover: hf==0 half handles it
            const int s = __shfl(sv, j);
            if (hf == 0) {
                const __half2 hv = *(const __half2*)(yb + (((unsigned)s << 7) | co));
                float2 f = __half22float2(hv);
                acc.x += f.x; acc.y += f.y;
            }
        }
        i += take;
    }
    return acc;
}

// ---------------------------------------------------------------------------
// Gather1 fused epilogue: h1 = relu(agg(y1) + b1) stored as fp16 (12.8 MB).
// ---------------------------------------------------------------------------
__global__ __launch_bounds__(256) void k_gather_h1(const int* __restrict__ off,
                                                   const int* __restrict__ srcS,
                                                   const __half* __restrict__ y16,
                                                   const float* __restrict__ b1,
                                                   __half* __restrict__ h16) {
    const int node = blockIdx.x * 4 + (threadIdx.x >> 6);
    if (node >= N_NODES) return;
    const int lane = threadIdx.x & 63;
    const int hf = lane >> 5, ln32 = lane & 31;
    float2 bb = {0.f, 0.f};
    if (hf == 0) bb = *(const float2*)&b1[ln32 * 2];

    float2 acc = gather_core(off, srcS, y16, node, lane);
    acc.x += __shfl_xor(acc.x, 32, 64);
    acc.y += __shfl_xor(acc.y, 32, 64);
    if (hf == 0) {
        float hx = fmaxf(acc.x + bb.x, 0.f);
        float hy = fmaxf(acc.y + bb.y, 0.f);
        *(__half2*)&h16[((size_t)node << 6) + (ln32 << 1)] = __floats2half2_rn(hx, hy);
    }
}

// ---------------------------------------------------------------------------
// Gather2 fused with the whole MLP head (z2 never materializes):
// z2 = agg(y2); h2 = relu(z2+b2); h3 = relu(h2@W3+b3); out = h3@W4+b4.
// Head in-wave: row exchanged via 1KB intra-wave LDS, 4 lanes per W3-column
// (W3 slices preloaded BEFORE the gather -> hidden), shfl_xor reductions.
// ---------------------------------------------------------------------------
__global__ __launch_bounds__(256) void k_gather_tail(const int* __restrict__ off,
                                                     const int* __restrict__ srcS,
                                                     const __half* __restrict__ y16,
                                                     const float* __restrict__ b2,
                                                     const float* __restrict__ W3,
                                                     const float* __restrict__ b3,
                                                     const float* __restrict__ W4,
                                                     const float* __restrict__ b4,
                                                     float* __restrict__ out) {
    __shared__ float sh2[4][64];
    const int wv   = threadIdx.x >> 6;
    const int node = blockIdx.x * 4 + wv;
    if (node >= N_NODES) return;
    const int lane = threadIdx.x & 63;
    const int hf = lane >> 5, ln32 = lane & 31;

    const int jj = lane & 15, pp = lane >> 4;    // 4 lanes cooperate per output jj
    float w3r[16];
    #pragma unroll
    for (int k = 0; k < 16; ++k) w3r[k] = W3[(pp * 16 + k) * 16 + jj];
    const float b3j = b3[jj], w4j = W4[jj], b4v = b4[0];
    float2 bb = {0.f, 0.f};
    if (hf == 0) bb = *(const float2*)&b2[ln32 * 2];

    float2 acc = gather_core(off, srcS, y16, node, lane);
    acc.x += __shfl_xor(acc.x, 32, 64);
    acc.y += __shfl_xor(acc.y, 32, 64);
    if (hf == 0) {
        float hx = fmaxf(acc.x + bb.x, 0.f);
        float hy = fmaxf(acc.y + bb.y, 0.f);
        *(float2*)&sh2[wv][ln32 * 2] = make_float2(hx, hy);
    }
    // intra-wave LDS exchange: per-wave DS ordering makes the write visible
    // to this wave's reads (no cross-wave consumers -> no barrier).
    const float4 hA = *(const float4*)&sh2[wv][pp * 16 + 0];
    const float4 hB = *(const float4*)&sh2[wv][pp * 16 + 4];
    const float4 hC = *(const float4*)&sh2[wv][pp * 16 + 8];
    const float4 hD = *(const float4*)&sh2[wv][pp * 16 + 12];
    float part = hA.x * w3r[0]  + hA.y * w3r[1]  + hA.z * w3r[2]  + hA.w * w3r[3]
               + hB.x * w3r[4]  + hB.y * w3r[5]  + hB.z * w3r[6]  + hB.w * w3r[7]
               + hC.x * w3r[8]  + hC.y * w3r[9]  + hC.z * w3r[10] + hC.w * w3r[11]
               + hD.x * w3r[12] + hD.y * w3r[13] + hD.z * w3r[14] + hD.w * w3r[15];
    part += __shfl_xor(part, 16, 64);            // reduce over pp (bits 4,5)
    part += __shfl_xor(part, 32, 64);
    float o = fmaxf(part + b3j, 0.f) * w4j;
    o += __shfl_xor(o, 1, 64);                   // reduce over jj (bits 0..3)
    o += __shfl_xor(o, 2, 64);
    o += __shfl_xor(o, 4, 64);
    o += __shfl_xor(o, 8, 64);
    if (lane == 0) out[node] = o + b4v;
}

// ---------------------------------------------------------------------------
// K1 (MFMA): y16 = fp16(x @ W1), 64 rows/block, 4 waves x 16 rows.
// A direct from global (fp32, cvt in regs); W1^T staged fp16 in LDS.
// mfma_f32_16x16x32_f16: A row=l&15, k=(l>>4)*8+i; B col=l&15, same k;
// D col=l&15, row=(l>>4)*4+reg (m89-verified mapping).
// ---------------------------------------------------------------------------
__global__ __launch_bounds__(256) void k_mm1(const float* __restrict__ x,
                                             const float* __restrict__ W1,
                                             __half* __restrict__ y16) {
    __shared__ __half sB[64 * 136];   // W1^T: sB[n][k], 17.4 KB
    const int tid = threadIdx.x;
    for (int i = tid * 4; i < 128 * 64; i += 1024) {
        int k = i >> 6, n = i & 63;                  // i = k*64 + n
        float4 w = *(const float4*)&W1[i];
        sB[(n + 0) * 136 + k] = __float2half(w.x);
        sB[(n + 1) * 136 + k] = __float2half(w.y);
        sB[(n + 2) * 136 + k] = __float2half(w.z);
        sB[(n + 3) * 136 + k] = __float2half(w.w);
    }
    __syncthreads();
    const int wv = tid >> 6, l = tid & 63;
    const int row0 = blockIdx.x * 64 + wv * 16;
    int arow = row0 + (l & 15);
    if (arow >= N_NODES) arow = N_NODES - 1;         // duplicate last row (stores predicated)
    const int kgrp = (l >> 4) * 8;

    f32x4 acc0 = {0,0,0,0}, acc1 = {0,0,0,0}, acc2 = {0,0,0,0}, acc3 = {0,0,0,0};
    #pragma unroll
    for (int ks = 0; ks < 4; ++ks) {
        const float4 a0 = *(const float4*)&x[(size_t)arow * 128 + ks * 32 + kgrp];
        const float4 a1 = *(const float4*)&x[(size_t)arow * 128 + ks * 32 + kgrp + 4];
        f16x8 af;
        af[0] = (_Float16)a0.x; af[1] = (_Float16)a0.y;
        af[2] = (_Float16)a0.z; af[3] = (_Float16)a0.w;
        af[4] = (_Float16)a1.x; af[5] = (_Float16)a1.y;
        af[6] = (_Float16)a1.z; af[7] = (_Float16)a1.w;
        union { uint4 u; f16x8 h; } B0, B1, B2, B3;
        B0.u = *(const uint4*)&sB[(0 * 16 + (l & 15)) * 136 + ks * 32 + kgrp];
        B1.u = *(const uint4*)&sB[(1 * 16 + (l & 15)) * 136 + ks * 32 + kgrp];
        B2.u = *(const uint4*)&sB[(2 * 16 + (l & 15)) * 136 + ks * 32 + kgrp];
        B3.u = *(const uint4*)&sB[(3 * 16 + (l & 15)) * 136 + ks * 32 + kgrp];
        acc0 = __builtin_amdgcn_mfma_f32_16x16x32_f16(af, B0.h, acc0, 0, 0, 0);
        acc1 = __builtin_amdgcn_mfma_f32_16x16x32_f16(af, B1.h, acc1, 0, 0, 0);
        acc2 = __builtin_amdgcn_mfma_f32_16x16x32_f16(af, B2.h, acc2, 0, 0, 0);
        acc3 = __builtin_amdgcn_mfma_f32_16x16x32_f16(af, B3.h, acc3, 0, 0, 0);
    }
    #pragma unroll
    for (int rr = 0; rr < 4; ++rr) {
        const int orow = row0 + (l >> 4) * 4 + rr;
        if (orow < N_NODES) {
            __half* yp = &y16[(size_t)orow * 64 + (l & 15)];
            yp[0]  = __float2half(acc0[rr]);
            yp[16] = __float2half(acc1[rr]);
            yp[32] = __float2half(acc2[rr]);
            yp[48] = __float2half(acc3[rr]);
        }
    }
}

// ---------------------------------------------------------------------------
// K3 (MFMA): y16 = fp16(h16 @ W2), K=64. A direct from global (already fp16,
// one dwordx4 per k-step). W2^T staged fp16 in LDS (stride 72: 144B rows).
// ---------------------------------------------------------------------------
__global__ __launch_bounds__(256) void k_mm2(const __half* __restrict__ h16,
                                             const float* __restrict__ W2,
                                             __half* __restrict__ y16) {
    __shared__ __half sB[64 * 72];    // W2^T: sB[n][k], 9.2 KB
    const int tid = threadIdx.x;
    for (int i = tid * 4; i < 64 * 64; i += 1024) {
        int k = i >> 6, n = i & 63;                  // i = k*64 + n
        float4 w = *(const float4*)&W2[i];
        sB[(n + 0) * 72 + k] = __float2half(w.x);
        sB[(n + 1) * 72 + k] = __float2half(w.y);
        sB[(n + 2) * 72 + k] = __float2half(w.z);
        sB[(n + 3) * 72 + k] = __float2half(w.w);
    }
    __syncthreads();
    const int wv = tid >> 6, l = tid & 63;
    const int row0 = blockIdx.x * 64 + wv * 16;
    int arow = row0 + (l & 15);
    if (arow >= N_NODES) arow = N_NODES - 1;
    const int kgrp = (l >> 4) * 8;

    f32x4 acc0 = {0,0,0,0}, acc1 = {0,0,0,0}, acc2 = {0,0,0,0}, acc3 = {0,0,0,0};
    #pragma unroll
    for (int ks = 0; ks < 2; ++ks) {
        union { uint4 u; f16x8 h; } A;
        A.u = *(const uint4*)&h16[(size_t)arow * 64 + ks * 32 + kgrp];
        union { uint4 u; f16x8 h; } B0, B1, B2, B3;
        B0.u = *(const uint4*)&sB[(0 * 16 + (l & 15)) * 72 + ks * 32 + kgrp];
        B1.u = *(const uint4*)&sB[(1 * 16 + (l & 15)) * 72 + ks * 32 + kgrp];
        B2.u = *(const uint4*)&sB[(2 * 16 + (l & 15)) * 72 + ks * 32 + kgrp];
        B3.u = *(const uint4*)&sB[(3 * 16 + (l & 15)) * 72 + ks * 32 + kgrp];
        acc0 = __builtin_amdgcn_mfma_f32_16x16x32_f16(A.h, B0.h, acc0, 0, 0, 0);
        acc1 = __builtin_amdgcn_mfma_f32_16x16x32_f16(A.h, B1.h, acc1, 0, 0, 0);
        acc2 = __builtin_amdgcn_mfma_f32_16x16x32_f16(A.h, B2.h, acc2, 0, 0, 0);
        acc3 = __builtin_amdgcn_mfma_f32_16x16x32_f16(A.h, B3.h, acc3, 0, 0, 0);
    }
    #pragma unroll
    for (int rr = 0; rr < 4; ++rr) {
        const int orow = row0 + (l >> 4) * 4 + rr;
        if (orow < N_NODES) {
            __half* yp = &y16[(size_t)orow * 64 + (l & 15)];
            yp[0]  = __float2half(acc0[rr]);
            yp[16] = __float2half(acc1[rr]);
            yp[32] = __float2half(acc2[rr]);
            yp[48] = __float2half(acc3[rr]);
        }
    }
}

extern "C" void kernel_launch(void* const* d_in, const int* in_sizes, int n_in,
                              void* d_out, int out_size, void* d_ws, size_t ws_size,
                              hipStream_t stream) {
    const float* x  = (const float*)d_in[0];
    const int*   ei = (const int*)d_in[1];
    const float* W1 = (const float*)d_in[2];
    const float* b1 = (const float*)d_in[3];
    const float* W2 = (const float*)d_in[4];
    const float* b2 = (const float*)d_in[5];
    const float* W3 = (const float*)d_in[6];
    const float* b3 = (const float*)d_in[7];
    const float* W4 = (const float*)d_in[8];
    const float* b4 = (const float*)d_in[9];
    float* out = (float*)d_out;

    // ws layout: h16 (12.8MB, aliases bArr 8MB) | y16 (12.8MB) | off | srcS | cursor
    // Order: p1/p2 use bArr -> mm1 writes y16 -> gather_h1 reads y16, writes
    // h16 (p2 done) -> mm2 reads h16, writes y16 (y1 dead) -> gather_tail.
    __half* h16    = (__half*)d_ws;
    __half* y16    = h16 + (size_t)N_NODES * 64;
    int*    off    = (int*)(y16 + (size_t)N_NODES * 64);
    int*    srcS   = off + N_NODES + 4;       // 16B alignment slack
    int*    cursor = srcS + N_EDGES;
    int*    bArr   = (int*)d_ws;

    const int mmBlocks  = (N_NODES + 63) / 64;        // 1563
    const int aggBlocks = (N_NODES + 3) / 4;          // 25000

    // CSR build (bucket sort, LDS atomics only)
    k_zero_cur<<<1, 256, 0, stream>>>(cursor);
    k_p1<<<NP1, 1024, 0, stream>>>(ei, cursor, bArr);
    k_p2<<<NBUCK, 1024, 0, stream>>>(bArr, cursor, srcS, off);

    // conv1: y16 = fp16(x@W1); h16 = fp16(relu(agg(y16)+b1))
    k_mm1<<<mmBlocks, 256, 0, stream>>>(x, W1, y16);
    k_gather_h1<<<aggBlocks, 256, 0, stream>>>(off, srcS, y16, b1, h16);
    // conv2 + head: y16 = fp16(h16@W2); out = head(agg(y16))
    k_mm2<<<mmBlocks, 256, 0, stream>>>(h16, W2, y16);
    k_gather_tail<<<aggBlocks, 256, 0, stream>>>(off, srcS, y16, b2, W3, b3, W4, b4, out);
}

// Round 11
// 241.828 us; speedup vs baseline: 1.3584x; 1.0373x over previous
//
#include <hip/hip_runtime.h>
#include <hip/hip_fp16.h>

#define N_NODES 100000
#define N_EDGES 1600000
#define NBUCK 196            // ceil(N_NODES / 512); bucket = dst >> 9
#define BUCAP 10240          // per-bucket capacity (mean 8163, sigma ~90)
#define P1_EDGES 8192        // edges per P1 block
#define NP1 196              // ceil(N_EDGES / P1_EDGES)
#define MM1_BLOCKS 391       // ceil(N_NODES / 256) rows at 1024 thr (16 waves x 16)
#define CURPAD 32            // cursor stride (ints): one 128B line per bucket

typedef _Float16 f16x8 __attribute__((ext_vector_type(8)));
typedef float    f32x4 __attribute__((ext_vector_type(4)));

// ---------------------------------------------------------------------------
// CSR build, atomic-light bucket sort (rebuilt every launch; ws re-poisoned).
// P1 (round-9 proven version): 8192 edges/block, LDS histogram, ONE global
// atomic per (block,bucket) on padded lines, random 4B scatter-out.
// ---------------------------------------------------------------------------
__global__ __launch_bounds__(1024) void k_p1(const int* __restrict__ ei,
                                             int* __restrict__ cursor,
                                             int* __restrict__ bArr) {
    __shared__ int hist[NBUCK];
    const int tid = threadIdx.x;
    if (tid < NBUCK) hist[tid] = 0;

    const int eb = blockIdx.x * P1_EDGES;
    int d[8], s[8];
    #pragma unroll
    for (int j = 0; j < 2; ++j) {
        const int e = eb + j * 4096 + tid * 4;
        if (e < N_EDGES) {                       // N_EDGES % 4 == 0: all-or-none
            int4 dd = *(const int4*)&ei[N_EDGES + e];
            int4 ss = *(const int4*)&ei[e];
            d[j*4+0] = dd.x; d[j*4+1] = dd.y; d[j*4+2] = dd.z; d[j*4+3] = dd.w;
            s[j*4+0] = ss.x; s[j*4+1] = ss.y; s[j*4+2] = ss.z; s[j*4+3] = ss.w;
        } else {
            d[j*4+0] = -1; d[j*4+1] = -1; d[j*4+2] = -1; d[j*4+3] = -1;
            s[j*4+0] = 0;  s[j*4+1] = 0;  s[j*4+2] = 0;  s[j*4+3] = 0;
        }
    }
    __syncthreads();
    #pragma unroll
    for (int j = 0; j < 8; ++j)
        if (d[j] >= 0) atomicAdd(&hist[d[j] >> 9], 1);
    __syncthreads();
    if (tid < NBUCK) {
        int c = hist[tid];
        int base = atomicAdd(&cursor[tid * CURPAD], c);  // padded: no line sharing
        hist[tid] = base;                                // reuse hist as write cursor
    }
    __syncthreads();
    #pragma unroll
    for (int j = 0; j < 8; ++j)
        if (d[j] >= 0) {
            int bk  = d[j] >> 9;
            int pos = atomicAdd(&hist[bk], 1);   // LDS rank -> base+rank
            if (pos < BUCAP)
                bArr[bk * BUCAP + pos] = ((d[j] & 511) << 17) | s[j];
        }
}

// ---------------------------------------------------------------------------
// Fused P2 + MM1 launch: blocks [0,NBUCK) build the node-level CSR for one
// bucket each (fills only 196 CUs); blocks [NBUCK, NBUCK+MM1_BLOCKS) run the
// independent y16 = fp16(x@W1) MFMA matmul on the otherwise-idle CUs.
// Branch is block-uniform -> per-path __syncthreads is safe. LDS is a union.
// mfma_f32_16x16x32_f16: A row=l&15, k=(l>>4)*8+i; B col=l&15, same k;
// D col=l&15, row=(l>>4)*4+reg (m89-verified mapping).
// ---------------------------------------------------------------------------
__global__ __launch_bounds__(1024) void k_p2mm1(const int* __restrict__ bArr,
                                                const int* __restrict__ cursor,
                                                int* __restrict__ srcS,
                                                int* __restrict__ off,
                                                const float* __restrict__ x,
                                                const float* __restrict__ W1,
                                                __half* __restrict__ y16) {
    __shared__ union SU {
        struct { int hist[512]; int wtot[8]; int curL[NBUCK]; int ordered[BUCAP]; } p2;
        __half sB[64 * 136];             // W1^T: sB[n][k], 17.4 KB
    } u;
    const int tid = threadIdx.x;

    if (blockIdx.x < NBUCK) {
        // ---------------- P2: per-bucket node-level CSR ----------------
        const int b = blockIdx.x;
        if (tid < 512)   u.p2.hist[tid] = 0;
        if (tid < NBUCK) u.p2.curL[tid] = cursor[tid * CURPAD];
        __syncthreads();

        int n = u.p2.curL[b]; if (n > BUCAP) n = BUCAP;
        int gBase = 0;
        for (int j = 0; j < NBUCK; ++j) gBase += (j < b) ? u.p2.curL[j] : 0;

        int pk[10];                              // static-indexed (rule #20)
        #pragma unroll
        for (int j = 0; j < 10; ++j) {
            int i = tid + j * 1024;
            pk[j] = (i < n) ? bArr[b * BUCAP + i] : -1;
        }
        #pragma unroll
        for (int j = 0; j < 10; ++j)
            if (pk[j] >= 0) atomicAdd(&u.p2.hist[pk[j] >> 17], 1);
        __syncthreads();

        // exclusive scan of hist[512]: 8 waves shfl-scan + cross-wave fixup
        int v = 0, incl = 0;
        if (tid < 512) {
            v = u.p2.hist[tid]; incl = v;
            #pragma unroll
            for (int dd = 1; dd < 64; dd <<= 1) {
                int t = __shfl_up(incl, dd, 64);
                if ((tid & 63) >= dd) incl += t;
            }
            if ((tid & 63) == 63) u.p2.wtot[tid >> 6] = incl;
        }
        __syncthreads();
        if (tid < 512) {
            int add = 0;
            #pragma unroll
            for (int w = 0; w < 8; ++w) add += (w < (tid >> 6)) ? u.p2.wtot[w] : 0;
            int ex = add + incl - v;
            u.p2.hist[tid] = ex;                 // becomes rank cursor for phase B
            int node = b * 512 + tid;
            if (node < N_NODES) off[node] = gBase + ex;
        }
        if (b == NBUCK - 1 && tid == 0) off[N_NODES] = N_EDGES;
        __syncthreads();

        #pragma unroll
        for (int j = 0; j < 10; ++j)
            if (pk[j] >= 0) {
                int dl  = pk[j] >> 17;
                int pos = atomicAdd(&u.p2.hist[dl], 1);
                u.p2.ordered[pos] = pk[j] & 0x1FFFF;
            }
        __syncthreads();
        for (int i = tid; i < n; i += 1024) srcS[gBase + i] = u.p2.ordered[i];
    } else {
        // ---------------- MM1: y16 = fp16(x @ W1), 256 rows/block --------
        for (int i = tid * 4; i < 128 * 64; i += 4096) {
            int k = i >> 6, nn = i & 63;             // i = k*64 + n
            float4 w = *(const float4*)&W1[i];
            u.sB[(nn + 0) * 136 + k] = __float2half(w.x);
            u.sB[(nn + 1) * 136 + k] = __float2half(w.y);
            u.sB[(nn + 2) * 136 + k] = __float2half(w.z);
            u.sB[(nn + 3) * 136 + k] = __float2half(w.w);
        }
        __syncthreads();
        const int wv = tid >> 6, l = tid & 63;       // 16 waves x 16 rows
        const int row0 = (blockIdx.x - NBUCK) * 256 + wv * 16;
        int arow = row0 + (l & 15);
        if (arow >= N_NODES) arow = N_NODES - 1;     // dup last row (stores predicated)
        const int kgrp = (l >> 4) * 8;

        f32x4 acc0 = {0,0,0,0}, acc1 = {0,0,0,0}, acc2 = {0,0,0,0}, acc3 = {0,0,0,0};
        #pragma unroll
        for (int ks = 0; ks < 4; ++ks) {
            const float4 a0 = *(const float4*)&x[(size_t)arow * 128 + ks * 32 + kgrp];
            const float4 a1 = *(const float4*)&x[(size_t)arow * 128 + ks * 32 + kgrp + 4];
            f16x8 af;
            af[0] = (_Float16)a0.x; af[1] = (_Float16)a0.y;
            af[2] = (_Float16)a0.z; af[3] = (_Float16)a0.w;
            af[4] = (_Float16)a1.x; af[5] = (_Float16)a1.y;
            af[6] = (_Float16)a1.z; af[7] = (_Float16)a1.w;
            union { uint4 q; f16x8 h; } B0, B1, B2, B3;
            B0.q = *(const uint4*)&u.sB[(0 * 16 + (l & 15)) * 136 + ks * 32 + kgrp];
            B1.q = *(const uint4*)&u.sB[(1 * 16 + (l & 15)) * 136 + ks * 32 + kgrp];
            B2.q = *(const uint4*)&u.sB[(2 * 16 + (l & 15)) * 136 + ks * 32 + kgrp];
            B3.q = *(const uint4*)&u.sB[(3 * 16 + (l & 15)) * 136 + ks * 32 + kgrp];
            acc0 = __builtin_amdgcn_mfma_f32_16x16x32_f16(af, B0.h, acc0, 0, 0, 0);
            acc1 = __builtin_amdgcn_mfma_f32_16x16x32_f16(af, B1.h, acc1, 0, 0, 0);
            acc2 = __builtin_amdgcn_mfma_f32_16x16x32_f16(af, B2.h, acc2, 0, 0, 0);
            acc3 = __builtin_amdgcn_mfma_f32_16x16x32_f16(af, B3.h, acc3, 0, 0, 0);
        }
        #pragma unroll
        for (int rr = 0; rr < 4; ++rr) {
            const int orow = row0 + (l >> 4) * 4 + rr;
            if (orow < N_NODES) {
                __half* yp = &y16[(size_t)orow * 64 + (l & 15)];
                yp[0]  = __float2half(acc0[rr]);
                yp[16] = __float2half(acc1[rr]);
                yp[32] = __float2half(acc2[rr]);
                yp[48] = __float2half(acc3[rr]);
            }
        }
    }
}

// ---------------------------------------------------------------------------
// Gather core: fp16 rows, 32 lanes/row x half2; wave splits into two halves,
// each gathering its own edge of a pair (8 loads in flight / 16-edge burst).
// (a) edge-pair pre-add in fp16 (__hadd2; sums bounded ~60 << 65504),
// (b) 32-bit byte-offset addressing (SGPR base + voffset, 1 VALU per addr).
// Returns per-lane float2 BEFORE the half-combine.
// ---------------------------------------------------------------------------
__device__ __forceinline__ float2 gather_core(const int* __restrict__ off,
                                              const int* __restrict__ srcS,
                                              const __half* __restrict__ y16,
                                              int node, int lane) {
    const int hf   = lane >> 5;
    const int ln32 = lane & 31;
    const unsigned co = (unsigned)(ln32 << 2);   // byte offset within 128B row
    const char* yb = (const char*)y16;
    const int beg = off[node];
    const int end = off[node + 1];

    float2 acc = {0.f, 0.f};
    if (hf == 0) {                               // self term
        __half2 hv = *(const __half2*)(yb + (((unsigned)node << 7) | co));
        float2 f = __half22float2(hv);
        acc.x = f.x; acc.y = f.y;
    }

    int i = beg;
    while (i < end) {
        const int rem  = end - i;
        const int take = rem < 64 ? rem : 64;
        int idx = i + lane;
        if (idx > end - 1) idx = end - 1;        // in-range duplicate for lanes >= take
        const int sv = srcS[idx];                // coalesced: 64 edge indices / wave
        int j = 0;
        for (; j + 16 <= take; j += 16) {        // 8 pairs = 16 edges, 8 loads in flight
            const int s0 = __shfl(sv, j + 0  + hf), s1 = __shfl(sv, j + 2  + hf);
            const int s2 = __shfl(sv, j + 4  + hf), s3 = __shfl(sv, j + 6  + hf);
            const int s4 = __shfl(sv, j + 8  + hf), s5 = __shfl(sv, j + 10 + hf);
            const int s6 = __shfl(sv, j + 12 + hf), s7 = __shfl(sv, j + 14 + hf);
            const __half2 h0 = *(const __half2*)(yb + (((unsigned)s0 << 7) | co));
            const __half2 h1 = *(const __half2*)(yb + (((unsigned)s1 << 7) | co));
            const __half2 h2 = *(const __half2*)(yb + (((unsigned)s2 << 7) | co));
            const __half2 h3 = *(const __half2*)(yb + (((unsigned)s3 << 7) | co));
            const __half2 h4 = *(const __half2*)(yb + (((unsigned)s4 << 7) | co));
            const __half2 h5 = *(const __half2*)(yb + (((unsigned)s5 << 7) | co));
            const __half2 h6 = *(const __half2*)(yb + (((unsigned)s6 << 7) | co));
            const __half2 h7 = *(const __half2*)(yb + (((unsigned)s7 << 7) | co));
            const __half2 t0 = __hadd2(h0, h1);  // fp16 pair pre-add (v_pk_add_f16)
            const __half2 t1 = __hadd2(h2, h3);
            const __half2 t2 = __hadd2(h4, h5);
            const __half2 t3 = __hadd2(h6, h7);
            float2 f0 = __half22float2(t0), f1 = __half22float2(t1);
            float2 f2 = __half22float2(t2), f3 = __half22float2(t3);
            acc.x += (f0.x + f1.x) + (f2.x + f3.x);
            acc.y += (f0.y + f1.y) + (f2.y + f3.y);
        }
        for (; j + 2 <= take; j += 2) {
            const int s = __shfl(sv, j + hf);
            const __half2 hv = *(const __half2*)(yb + (((unsigned)s << 7) | co));
            float2 f = __half22float2(hv);
            acc.x += f.x; acc.y += f.y;
        }
        if (j < take) {                          // odd leftover: hf==0 half handles it
            const int s = __shfl(sv, j);
            if (hf == 0) {
                const __half2 hv = *(const __half2*)(yb + (((unsigned)s << 7) | co));
                float2 f = __half22float2(hv);
                acc.x += f.x; acc.y += f.y;
            }
        }
        i += take;
    }
    return acc;
}

// ---------------------------------------------------------------------------
// Gather1 fused epilogue: h1 = relu(agg(y1) + b1) stored as fp16 (12.8 MB).
// ---------------------------------------------------------------------------
__global__ __launch_bounds__(256) void k_gather_h1(const int* __restrict__ off,
                                                   const int* __restrict__ srcS,
                                                   const __half* __restrict__ y16,
                                                   const float* __restrict__ b1,
                                                   __half* __restrict__ h16) {
    const int node = blockIdx.x * 4 + (threadIdx.x >> 6);
    if (node >= N_NODES) return;
    const int lane = threadIdx.x & 63;
    const int hf = lane >> 5, ln32 = lane & 31;
    float2 bb = {0.f, 0.f};
    if (hf == 0) bb = *(const float2*)&b1[ln32 * 2];

    float2 acc = gather_core(off, srcS, y16, node, lane);
    acc.x += __shfl_xor(acc.x, 32, 64);
    acc.y += __shfl_xor(acc.y, 32, 64);
    if (hf == 0) {
        float hx = fmaxf(acc.x + bb.x, 0.f);
        float hy = fmaxf(acc.y + bb.y, 0.f);
        *(__half2*)&h16[((size_t)node << 6) + (ln32 << 1)] = __floats2half2_rn(hx, hy);
    }
}

// ---------------------------------------------------------------------------
// Gather2 fused with the whole MLP head (z2 never materializes):
// z2 = agg(y2); h2 = relu(z2+b2); h3 = relu(h2@W3+b3); out = h3@W4+b4.
// Head in-wave: row exchanged via 1KB intra-wave LDS, 4 lanes per W3-column
// (W3 slices preloaded BEFORE the gather -> hidden), shfl_xor reductions.
// ---------------------------------------------------------------------------
__global__ __launch_bounds__(256) void k_gather_tail(const int* __restrict__ off,
                                                     const int* __restrict__ srcS,
                                                     const __half* __restrict__ y16,
                                                     const float* __restrict__ b2,
                                                     const float* __restrict__ W3,
                                                     const float* __restrict__ b3,
                                                     const float* __restrict__ W4,
                                                     const float* __restrict__ b4,
                                                     float* __restrict__ out) {
    __shared__ float sh2[4][64];
    const int wv   = threadIdx.x >> 6;
    const int node = blockIdx.x * 4 + wv;
    if (node >= N_NODES) return;
    const int lane = threadIdx.x & 63;
    const int hf = lane >> 5, ln32 = lane & 31;

    const int jj = lane & 15, pp = lane >> 4;    // 4 lanes cooperate per output jj
    float w3r[16];
    #pragma unroll
    for (int k = 0; k < 16; ++k) w3r[k] = W3[(pp * 16 + k) * 16 + jj];
    const float b3j = b3[jj], w4j = W4[jj], b4v = b4[0];
    float2 bb = {0.f, 0.f};
    if (hf == 0) bb = *(const float2*)&b2[ln32 * 2];

    float2 acc = gather_core(off, srcS, y16, node, lane);
    acc.x += __shfl_xor(acc.x, 32, 64);
    acc.y += __shfl_xor(acc.y, 32, 64);
    if (hf == 0) {
        float hx = fmaxf(acc.x + bb.x, 0.f);
        float hy = fmaxf(acc.y + bb.y, 0.f);
        *(float2*)&sh2[wv][ln32 * 2] = make_float2(hx, hy);
    }
    // intra-wave LDS exchange: per-wave DS ordering makes the write visible
    // to this wave's reads (no cross-wave consumers -> no barrier).
    const float4 hA = *(const float4*)&sh2[wv][pp * 16 + 0];
    const float4 hB = *(const float4*)&sh2[wv][pp * 16 + 4];
    const float4 hC = *(const float4*)&sh2[wv][pp * 16 + 8];
    const float4 hD = *(const float4*)&sh2[wv][pp * 16 + 12];
    float part = hA.x * w3r[0]  + hA.y * w3r[1]  + hA.z * w3r[2]  + hA.w * w3r[3]
               + hB.x * w3r[4]  + hB.y * w3r[5]  + hB.z * w3r[6]  + hB.w * w3r[7]
               + hC.x * w3r[8]  + hC.y * w3r[9]  + hC.z * w3r[10] + hC.w * w3r[11]
               + hD.x * w3r[12] + hD.y * w3r[13] + hD.z * w3r[14] + hD.w * w3r[15];
    part += __shfl_xor(part, 16, 64);            // reduce over pp (bits 4,5)
    part += __shfl_xor(part, 32, 64);
    float o = fmaxf(part + b3j, 0.f) * w4j;
    o += __shfl_xor(o, 1, 64);                   // reduce over jj (bits 0..3)
    o += __shfl_xor(o, 2, 64);
    o += __shfl_xor(o, 4, 64);
    o += __shfl_xor(o, 8, 64);
    if (lane == 0) out[node] = o + b4v;
}

// ---------------------------------------------------------------------------
// K3 (MFMA): y16 = fp16(h16 @ W2), K=64. A direct from global (already fp16,
// one dwordx4 per k-step). W2^T staged fp16 in LDS (stride 72: 144B rows).
// ---------------------------------------------------------------------------
__global__ __launch_bounds__(256) void k_mm2(const __half* __restrict__ h16,
                                             const float* __restrict__ W2,
                                             __half* __restrict__ y16) {
    __shared__ __half sB[64 * 72];    // W2^T: sB[n][k], 9.2 KB
    const int tid = threadIdx.x;
    for (int i = tid * 4; i < 64 * 64; i += 1024) {
        int k = i >> 6, n = i & 63;                  // i = k*64 + n
        float4 w = *(const float4*)&W2[i];
        sB[(n + 0) * 72 + k] = __float2half(w.x);
        sB[(n + 1) * 72 + k] = __float2half(w.y);
        sB[(n + 2) * 72 + k] = __float2half(w.z);
        sB[(n + 3) * 72 + k] = __float2half(w.w);
    }
    __syncthreads();
    const int wv = tid >> 6, l = tid & 63;
    const int row0 = blockIdx.x * 64 + wv * 16;
    int arow = row0 + (l & 15);
    if (arow >= N_NODES) arow = N_NODES - 1;
    const int kgrp = (l >> 4) * 8;

    f32x4 acc0 = {0,0,0,0}, acc1 = {0,0,0,0}, acc2 = {0,0,0,0}, acc3 = {0,0,0,0};
    #pragma unroll
    for (int ks = 0; ks < 2; ++ks) {
        union { uint4 q; f16x8 h; } A;
        A.q = *(const uint4*)&h16[(size_t)arow * 64 + ks * 32 + kgrp];
        union { uint4 q; f16x8 h; } B0, B1, B2, B3;
        B0.q = *(const uint4*)&sB[(0 * 16 + (l & 15)) * 72 + ks * 32 + kgrp];
        B1.q = *(const uint4*)&sB[(1 * 16 + (l & 15)) * 72 + ks * 32 + kgrp];
        B2.q = *(const uint4*)&sB[(2 * 16 + (l & 15)) * 72 + ks * 32 + kgrp];
        B3.q = *(const uint4*)&sB[(3 * 16 + (l & 15)) * 72 + ks * 32 + kgrp];
        acc0 = __builtin_amdgcn_mfma_f32_16x16x32_f16(A.h, B0.h, acc0, 0, 0, 0);
        acc1 = __builtin_amdgcn_mfma_f32_16x16x32_f16(A.h, B1.h, acc1, 0, 0, 0);
        acc2 = __builtin_amdgcn_mfma_f32_16x16x32_f16(A.h, B2.h, acc2, 0, 0, 0);
        acc3 = __builtin_amdgcn_mfma_f32_16x16x32_f16(A.h, B3.h, acc3, 0, 0, 0);
    }
    #pragma unroll
    for (int rr = 0; rr < 4; ++rr) {
        const int orow = row0 + (l >> 4) * 4 + rr;
        if (orow < N_NODES) {
            __half* yp = &y16[(size_t)orow * 64 + (l & 15)];
            yp[0]  = __float2half(acc0[rr]);
            yp[16] = __float2half(acc1[rr]);
            yp[32] = __float2half(acc2[rr]);
            yp[48] = __float2half(acc3[rr]);
        }
    }
}

extern "C" void kernel_launch(void* const* d_in, const int* in_sizes, int n_in,
                              void* d_out, int out_size, void* d_ws, size_t ws_size,
                              hipStream_t stream) {
    const float* x  = (const float*)d_in[0];
    const int*   ei = (const int*)d_in[1];
    const float* W1 = (const float*)d_in[2];
    const float* b1 = (const float*)d_in[3];
    const float* W2 = (const float*)d_in[4];
    const float* b2 = (const float*)d_in[5];
    const float* W3 = (const float*)d_in[6];
    const float* b3 = (const float*)d_in[7];
    const float* W4 = (const float*)d_in[8];
    const float* b4 = (const float*)d_in[9];
    float* out = (float*)d_out;

    // ws layout: h16 (12.8MB, aliases bArr 8MB) | y16 (12.8MB) | off | srcS | cursor
    // Order: p1/p2 use bArr; mm1 (fused with p2) writes y16 (disjoint region);
    // gather_h1 reads y16, writes h16 (p2 done) -> mm2 -> gather_tail.
    __half* h16    = (__half*)d_ws;
    __half* y16    = h16 + (size_t)N_NODES * 64;
    int*    off    = (int*)(y16 + (size_t)N_NODES * 64);
    int*    srcS   = off + N_NODES + 4;       // 16B alignment slack
    int*    cursor = srcS + N_EDGES;
    int*    bArr   = (int*)d_ws;

    const int mmBlocks  = (N_NODES + 63) / 64;        // 1563 (mm2)
    const int aggBlocks = (N_NODES + 3) / 4;          // 25000

    // CSR build (bucket sort, LDS atomics only); cursor zeroed by memset.
    hipMemsetAsync(cursor, 0, NBUCK * CURPAD * sizeof(int), stream);
    k_p1<<<NP1, 1024, 0, stream>>>(ei, cursor, bArr);
    // p2 (196 blocks) + independent mm1 (391 blocks) co-resident in one launch
    k_p2mm1<<<NBUCK + MM1_BLOCKS, 1024, 0, stream>>>(bArr, cursor, srcS, off,
                                                     x, W1, y16);

    // conv1 aggregate: h16 = fp16(relu(agg(y16)+b1))
    k_gather_h1<<<aggBlocks, 256, 0, stream>>>(off, srcS, y16, b1, h16);
    // conv2 + head: y16 = fp16(h16@W2); out = head(agg(y16))
    k_mm2<<<mmBlocks, 256, 0, stream>>>(h16, W2, y16);
    k_gather_tail<<<aggBlocks, 256, 0, stream>>>(off, srcS, y16, b2, W3, b3, W4, b4, out);
}